// Round 1
// baseline (75.996 us; speedup 1.0000x reference)
//
#include <hip/hip_runtime.h>

// Geometry constants (from reference): B=4, C=8, D=48, H=128, W=160
#define HW    20480      // H*W
#define DHW   983040     // D*H*W (channel stride)
#define CDHW  7864320    // C*D*H*W (batch stride)
#define DD    48
#define NPIX  81920      // B*H*W output pixels

typedef _Float16 half2v __attribute__((ext_vector_type(2)));

// Folded weights (BN absorbed into conv weights), packed as f16 pairs.
__device__ half2v g_w0h[16][4];
__device__ float  g_b0[16];
__device__ half2v g_w1h[8][8];
__device__ float  g_b1[8];
__device__ half2v g_w2h[4];
__device__ float  g_bias2;

static __device__ inline float dot2(half2v a, half2v b, float c) {
#if __has_builtin(__builtin_amdgcn_fdot2)
    return __builtin_amdgcn_fdot2(a, b, c, false);
#else
    return fmaf((float)a.x, (float)b.x, fmaf((float)a.y, (float)b.y, c));
#endif
}

__global__ void fold_kernel(const float* __restrict__ w0, const float* __restrict__ g0,
                            const float* __restrict__ b0, const float* __restrict__ m0,
                            const float* __restrict__ v0,
                            const float* __restrict__ w1, const float* __restrict__ g1,
                            const float* __restrict__ b1, const float* __restrict__ m1,
                            const float* __restrict__ v1,
                            const float* __restrict__ w2, const float* __restrict__ bias2)
{
    int t = threadIdx.x;
    if (t < 16) {
        float sc = g0[t] * rsqrtf(v0[t] + 1e-5f);
        for (int i = 0; i < 4; ++i) {
            half2v h;
            h.x = (_Float16)(w0[t * 8 + 2 * i]     * sc);
            h.y = (_Float16)(w0[t * 8 + 2 * i + 1] * sc);
            g_w0h[t][i] = h;
        }
        g_b0[t] = b0[t] - m0[t] * sc;
    } else if (t < 24) {
        int j = t - 16;
        float sc = g1[j] * rsqrtf(v1[j] + 1e-5f);
        for (int i = 0; i < 8; ++i) {
            half2v h;
            h.x = (_Float16)(w1[j * 16 + 2 * i]     * sc);
            h.y = (_Float16)(w1[j * 16 + 2 * i + 1] * sc);
            g_w1h[j][i] = h;
        }
        g_b1[j] = b1[j] - m1[j] * sc;
    } else if (t == 24) {
        for (int i = 0; i < 4; ++i) {
            half2v h;
            h.x = (_Float16)w2[2 * i];
            h.y = (_Float16)w2[2 * i + 1];
            g_w2h[i] = h;
        }
        g_bias2 = bias2[0];
    }
}

__global__ __launch_bounds__(256, 2)
void mlp_kernel(const float* __restrict__ x, float* __restrict__ out)
{
    int p = blockIdx.x * 256 + threadIdx.x;   // [0, NPIX)
    int b = p / HW;
    int s = p - b * HW;
    const float* xp = x + (size_t)b * CDHW + s;

    // Hoist folded weights into registers (uniform loads).
    half2v w0h[16][4]; float b0f[16];
    half2v w1h[8][8];  float b1f[8];
    half2v w2h[4];     float b2f;
#pragma unroll
    for (int o = 0; o < 16; ++o) {
#pragma unroll
        for (int i = 0; i < 4; ++i) w0h[o][i] = g_w0h[o][i];
        b0f[o] = g_b0[o];
    }
#pragma unroll
    for (int j = 0; j < 8; ++j) {
#pragma unroll
        for (int i = 0; i < 8; ++i) w1h[j][i] = g_w1h[j][i];
        b1f[j] = g_b1[j];
    }
#pragma unroll
    for (int i = 0; i < 4; ++i) w2h[i] = g_w2h[i];
    b2f = g_bias2;

    float maxv = -1e30f;

    // Prefetch d=0
    float xv[8];
#pragma unroll
    for (int c = 0; c < 8; ++c) xv[c] = xp[(size_t)c * DHW];

#pragma unroll 2
    for (int d = 0; d < DD; ++d) {
        float xn[8];
        if (d + 1 < DD) {
            const float* xq = xp + (size_t)(d + 1) * HW;
#pragma unroll
            for (int c = 0; c < 8; ++c) xn[c] = xq[(size_t)c * DHW];
        }

        // pack input to f16 pairs
        half2v xh[4];
#pragma unroll
        for (int i = 0; i < 4; ++i) {
            half2v h; h.x = (_Float16)xv[2 * i]; h.y = (_Float16)xv[2 * i + 1];
            xh[i] = h;
        }

        // layer 0: 8 -> 16, ReLU
        float h0[16];
#pragma unroll
        for (int o = 0; o < 16; ++o) {
            float a = b0f[o];
#pragma unroll
            for (int i = 0; i < 4; ++i) a = dot2(xh[i], w0h[o][i], a);
            h0[o] = fmaxf(a, 0.0f);
        }
        half2v hh[8];
#pragma unroll
        for (int i = 0; i < 8; ++i) {
            half2v h; h.x = (_Float16)h0[2 * i]; h.y = (_Float16)h0[2 * i + 1];
            hh[i] = h;
        }

        // layer 1: 16 -> 8, ReLU
        float h1[8];
#pragma unroll
        for (int j = 0; j < 8; ++j) {
            float a = b1f[j];
#pragma unroll
            for (int i = 0; i < 8; ++i) a = dot2(hh[i], w1h[j][i], a);
            h1[j] = fmaxf(a, 0.0f);
        }
        half2v h1h[4];
#pragma unroll
        for (int i = 0; i < 4; ++i) {
            half2v h; h.x = (_Float16)h1[2 * i]; h.y = (_Float16)h1[2 * i + 1];
            h1h[i] = h;
        }

        // layer 2: 8 -> 1 (logit)
        float a = b2f;
#pragma unroll
        for (int i = 0; i < 4; ++i) a = dot2(h1h[i], w2h[i], a);

        maxv = fmaxf(maxv, a);

#pragma unroll
        for (int c = 0; c < 8; ++c) xv[c] = xn[c];
    }

    // sigmoid is monotone: max_d sigmoid(z) == sigmoid(max_d z)
    out[p] = 1.0f / (1.0f + __expf(-maxv));
}

extern "C" void kernel_launch(void* const* d_in, const int* in_sizes, int n_in,
                              void* d_out, int out_size, void* d_ws, size_t ws_size,
                              hipStream_t stream) {
    const float* x1 = (const float*)d_in[0];
    fold_kernel<<<1, 64, 0, stream>>>(
        (const float*)d_in[1], (const float*)d_in[2], (const float*)d_in[3],
        (const float*)d_in[4], (const float*)d_in[5],
        (const float*)d_in[6], (const float*)d_in[7], (const float*)d_in[8],
        (const float*)d_in[9], (const float*)d_in[10],
        (const float*)d_in[11], (const float*)d_in[12]);
    mlp_kernel<<<NPIX / 256, 256, 0, stream>>>(x1, (float*)d_out);
}

// Round 3
// 63.386 us; speedup vs baseline: 1.1989x; 1.1989x over previous
//
#include <hip/hip_runtime.h>

// Geometry constants (from reference): B=4, C=8, D=48, H=128, W=160
#define HW    20480      // H*W
#define DHW   983040     // D*H*W (channel stride)
#define CDHW  7864320    // C*D*H*W (batch stride)
#define DD    48
#define NPIX  81920      // B*H*W output pixels
#define NCHUNK 6         // d-chunks per pixel (waves per block)
#define DCH    8         // d-slices per chunk (48/6)

typedef _Float16 half2v __attribute__((ext_vector_type(2)));

// Folded weights (BN absorbed into conv weights), packed as f16 pairs.
__device__ half2v g_w0h[16][4];
__device__ float  g_b0[16];
__device__ half2v g_w1h[8][8];
__device__ float  g_b1[8];
__device__ half2v g_w2h[4];
__device__ float  g_bias2;

static __device__ inline float dot2(half2v a, half2v b, float c) {
#if __has_builtin(__builtin_amdgcn_fdot2)
    return __builtin_amdgcn_fdot2(a, b, c, false);
#else
    return fmaf((float)a.x, (float)b.x, fmaf((float)a.y, (float)b.y, c));
#endif
}

static __device__ inline half2v pk(float a, float b) {
#if __has_builtin(__builtin_amdgcn_cvt_pkrtz)
    return __builtin_bit_cast(half2v, __builtin_amdgcn_cvt_pkrtz(a, b));
#else
    half2v h; h.x = (_Float16)a; h.y = (_Float16)b; return h;
#endif
}

__global__ void fold_kernel(const float* __restrict__ w0, const float* __restrict__ g0,
                            const float* __restrict__ b0, const float* __restrict__ m0,
                            const float* __restrict__ v0,
                            const float* __restrict__ w1, const float* __restrict__ g1,
                            const float* __restrict__ b1, const float* __restrict__ m1,
                            const float* __restrict__ v1,
                            const float* __restrict__ w2, const float* __restrict__ bias2)
{
    int t = threadIdx.x;
    if (t < 16) {
        float sc = g0[t] * rsqrtf(v0[t] + 1e-5f);
        for (int i = 0; i < 4; ++i) {
            half2v h;
            h.x = (_Float16)(w0[t * 8 + 2 * i]     * sc);
            h.y = (_Float16)(w0[t * 8 + 2 * i + 1] * sc);
            g_w0h[t][i] = h;
        }
        g_b0[t] = b0[t] - m0[t] * sc;
    } else if (t < 24) {
        int j = t - 16;
        float sc = g1[j] * rsqrtf(v1[j] + 1e-5f);
        for (int i = 0; i < 8; ++i) {
            half2v h;
            h.x = (_Float16)(w1[j * 16 + 2 * i]     * sc);
            h.y = (_Float16)(w1[j * 16 + 2 * i + 1] * sc);
            g_w1h[j][i] = h;
        }
        g_b1[j] = b1[j] - m1[j] * sc;
    } else if (t == 24) {
        for (int i = 0; i < 4; ++i) {
            half2v h;
            h.x = (_Float16)w2[2 * i];
            h.y = (_Float16)w2[2 * i + 1];
            g_w2h[i] = h;
        }
        g_bias2 = bias2[0];
    }
}

__global__ __launch_bounds__(NCHUNK * 64)
void mlp_kernel(const float* __restrict__ x, float* __restrict__ out)
{
    const int lane = threadIdx.x & 63;
    const int wv   = threadIdx.x >> 6;          // d-chunk id, 0..5
    const int p    = blockIdx.x * 64 + lane;    // pixel id
    const int b    = p / HW;
    const int s    = p - b * HW;
    const float* xp = x + (size_t)b * CDHW + s + (size_t)(wv * DCH) * HW;

    // Hoist folded weights into registers (uniform -> scalar loads).
    half2v w0h[16][4]; float b0f[16];
    half2v w1h[8][8];  float b1f[8];
    half2v w2h[4];     float b2f;
#pragma unroll
    for (int o = 0; o < 16; ++o) {
#pragma unroll
        for (int i = 0; i < 4; ++i) w0h[o][i] = g_w0h[o][i];
        b0f[o] = g_b0[o];
    }
#pragma unroll
    for (int j = 0; j < 8; ++j) {
#pragma unroll
        for (int i = 0; i < 8; ++i) w1h[j][i] = g_w1h[j][i];
        b1f[j] = g_b1[j];
    }
#pragma unroll
    for (int i = 0; i < 4; ++i) w2h[i] = g_w2h[i];
    b2f = g_bias2;

    float maxv = -1e30f;

    // Prefetch first d-slice of this chunk
    float xv[8];
#pragma unroll
    for (int c = 0; c < 8; ++c) xv[c] = xp[(size_t)c * DHW];

#pragma unroll 2
    for (int d = 0; d < DCH; ++d) {
        float xn[8];
        if (d + 1 < DCH) {
            const float* xq = xp + (size_t)(d + 1) * HW;
#pragma unroll
            for (int c = 0; c < 8; ++c) xn[c] = xq[(size_t)c * DHW];
        }

        // pack input to f16 pairs
        half2v xh[4];
#pragma unroll
        for (int i = 0; i < 4; ++i) xh[i] = pk(xv[2 * i], xv[2 * i + 1]);

        // layer 0: 8 -> 16, ReLU
        float h0[16];
#pragma unroll
        for (int o = 0; o < 16; ++o) {
            float a = b0f[o];
#pragma unroll
            for (int i = 0; i < 4; ++i) a = dot2(xh[i], w0h[o][i], a);
            h0[o] = fmaxf(a, 0.0f);
        }
        half2v hh[8];
#pragma unroll
        for (int i = 0; i < 8; ++i) hh[i] = pk(h0[2 * i], h0[2 * i + 1]);

        // layer 1: 16 -> 8, ReLU
        float h1[8];
#pragma unroll
        for (int j = 0; j < 8; ++j) {
            float a = b1f[j];
#pragma unroll
            for (int i = 0; i < 8; ++i) a = dot2(hh[i], w1h[j][i], a);
            h1[j] = fmaxf(a, 0.0f);
        }
        half2v h1h[4];
#pragma unroll
        for (int i = 0; i < 4; ++i) h1h[i] = pk(h1[2 * i], h1[2 * i + 1]);

        // layer 2: 8 -> 1 (logit)
        float a = b2f;
#pragma unroll
        for (int i = 0; i < 4; ++i) a = dot2(h1h[i], w2h[i], a);

        maxv = fmaxf(maxv, a);

#pragma unroll
        for (int c = 0; c < 8; ++c) xv[c] = xn[c];
    }

    // Cross-wave max reduction over the 6 d-chunks.
    __shared__ float red[NCHUNK][64];
    red[wv][lane] = maxv;
    __syncthreads();
    if (threadIdx.x < 64) {
        float m = red[0][lane];
#pragma unroll
        for (int i = 1; i < NCHUNK; ++i) m = fmaxf(m, red[i][lane]);
        // sigmoid is monotone: max_d sigmoid(z) == sigmoid(max_d z)
        out[p] = 1.0f / (1.0f + __expf(-m));
    }
}

extern "C" void kernel_launch(void* const* d_in, const int* in_sizes, int n_in,
                              void* d_out, int out_size, void* d_ws, size_t ws_size,
                              hipStream_t stream) {
    const float* x1 = (const float*)d_in[0];
    fold_kernel<<<1, 64, 0, stream>>>(
        (const float*)d_in[1], (const float*)d_in[2], (const float*)d_in[3],
        (const float*)d_in[4], (const float*)d_in[5],
        (const float*)d_in[6], (const float*)d_in[7], (const float*)d_in[8],
        (const float*)d_in[9], (const float*)d_in[10],
        (const float*)d_in[11], (const float*)d_in[12]);
    mlp_kernel<<<NPIX / 64, NCHUNK * 64, 0, stream>>>(x1, (float*)d_out);
}

// Round 4
// 58.804 us; speedup vs baseline: 1.2924x; 1.0779x over previous
//
#include <hip/hip_runtime.h>

// Geometry (from reference): B=4, C=8, D=48, H=128, W=160
#define HW    20480      // H*W
#define DHW   983040     // D*H*W (channel stride)
#define CDHW  7864320    // C*D*H*W (batch stride)
#define DD    48
#define NPIX  81920      // B*H*W output pixels
#define NW    4          // waves per block = d-chunks per pixel group
#define DCH   12         // d-slices per chunk (48/4)

typedef _Float16 half2v __attribute__((ext_vector_type(2)));

// Folded weights (BN absorbed), packed as f16 pairs.
__device__ half2v g_w0h[16][4];
__device__ float  g_b0[16];
__device__ half2v g_w1h[8][8];
__device__ float  g_b1[8];
__device__ half2v g_w2h[4];
__device__ float  g_bias2;

static __device__ inline float dot2(half2v a, half2v b, float c) {
#if __has_builtin(__builtin_amdgcn_fdot2)
    return __builtin_amdgcn_fdot2(a, b, c, false);
#else
    return fmaf((float)a.x, (float)b.x, fmaf((float)a.y, (float)b.y, c));
#endif
}

static __device__ inline half2v pk(float a, float b) {
#if __has_builtin(__builtin_amdgcn_cvt_pkrtz)
    return __builtin_bit_cast(half2v, __builtin_amdgcn_cvt_pkrtz(a, b));
#else
    half2v h; h.x = (_Float16)a; h.y = (_Float16)b; return h;
#endif
}

// Pin a value into a VGPR: compiler cannot rematerialize/reload it afterwards.
#define PINV(x) asm volatile("" : "+v"(x))

__global__ void fold_kernel(const float* __restrict__ w0, const float* __restrict__ g0,
                            const float* __restrict__ b0, const float* __restrict__ m0,
                            const float* __restrict__ v0,
                            const float* __restrict__ w1, const float* __restrict__ g1,
                            const float* __restrict__ b1, const float* __restrict__ m1,
                            const float* __restrict__ v1,
                            const float* __restrict__ w2, const float* __restrict__ bias2)
{
    int t = threadIdx.x;
    if (t < 16) {
        float sc = g0[t] * rsqrtf(v0[t] + 1e-5f);
        for (int i = 0; i < 4; ++i) {
            half2v h;
            h.x = (_Float16)(w0[t * 8 + 2 * i]     * sc);
            h.y = (_Float16)(w0[t * 8 + 2 * i + 1] * sc);
            g_w0h[t][i] = h;
        }
        g_b0[t] = b0[t] - m0[t] * sc;
    } else if (t < 24) {
        int j = t - 16;
        float sc = g1[j] * rsqrtf(v1[j] + 1e-5f);
        for (int i = 0; i < 8; ++i) {
            half2v h;
            h.x = (_Float16)(w1[j * 16 + 2 * i]     * sc);
            h.y = (_Float16)(w1[j * 16 + 2 * i + 1] * sc);
            g_w1h[j][i] = h;
        }
        g_b1[j] = b1[j] - m1[j] * sc;
    } else if (t == 24) {
        for (int i = 0; i < 4; ++i) {
            half2v h;
            h.x = (_Float16)w2[2 * i];
            h.y = (_Float16)w2[2 * i + 1];
            g_w2h[i] = h;
        }
        g_bias2 = bias2[0];
    }
}

__global__ __launch_bounds__(NW * 64, 1)
void mlp_kernel(const float* __restrict__ x, float* __restrict__ out)
{
    const int lane = threadIdx.x & 63;
    const int wv   = threadIdx.x >> 6;          // d-chunk id, 0..NW-1
    const int p    = blockIdx.x * 64 + lane;    // pixel id
    const int b    = p / HW;
    const int s    = p - b * HW;
    const float* xp = x + (size_t)b * CDHW + s + (size_t)(wv * DCH) * HW;

    // --- Hoist folded weights into VGPRs and PIN them there. ---
    half2v w0h[16][4]; float b0f[16];
    half2v w1h[8][8];  float b1f[8];
    half2v w2h[4];     float b2f;
#pragma unroll
    for (int o = 0; o < 16; ++o) {
#pragma unroll
        for (int i = 0; i < 4; ++i) { w0h[o][i] = g_w0h[o][i]; PINV(w0h[o][i]); }
        b0f[o] = g_b0[o]; PINV(b0f[o]);
    }
#pragma unroll
    for (int j = 0; j < 8; ++j) {
#pragma unroll
        for (int i = 0; i < 8; ++i) { w1h[j][i] = g_w1h[j][i]; PINV(w1h[j][i]); }
        b1f[j] = g_b1[j]; PINV(b1f[j]);
    }
#pragma unroll
    for (int i = 0; i < 4; ++i) { w2h[i] = g_w2h[i]; PINV(w2h[i]); }
    b2f = g_bias2; PINV(b2f);

    float maxv = -1e30f;

    // Prefetch depth 2: bufA holds slice d, bufB holds slice d+1.
    float bufA[8], bufB[8];
#pragma unroll
    for (int c = 0; c < 8; ++c) bufA[c] = xp[(size_t)c * DHW];
#pragma unroll
    for (int c = 0; c < 8; ++c) bufB[c] = xp[(size_t)c * DHW + HW];

    // One step: consume `cur` (slice d), then reuse its registers to
    // prefetch slice d+2. All indices compile-time constant.
#define STEP(cur, d)                                                        \
    {                                                                       \
        half2v xh[4];                                                       \
        _Pragma("unroll")                                                   \
        for (int i = 0; i < 4; ++i) xh[i] = pk(cur[2*i], cur[2*i+1]);       \
        if ((d) + 2 < DCH) {                                                \
            const float* xq = xp + (size_t)((d) + 2) * HW;                  \
            _Pragma("unroll")                                               \
            for (int c = 0; c < 8; ++c) cur[c] = xq[(size_t)c * DHW];       \
        }                                                                   \
        float h0[16];                                                       \
        _Pragma("unroll")                                                   \
        for (int o = 0; o < 16; ++o) {                                      \
            float a = b0f[o];                                               \
            _Pragma("unroll")                                               \
            for (int i = 0; i < 4; ++i) a = dot2(xh[i], w0h[o][i], a);      \
            h0[o] = fmaxf(a, 0.0f);                                         \
        }                                                                   \
        half2v hh[8];                                                       \
        _Pragma("unroll")                                                   \
        for (int i = 0; i < 8; ++i) hh[i] = pk(h0[2*i], h0[2*i+1]);         \
        float h1[8];                                                        \
        _Pragma("unroll")                                                   \
        for (int j = 0; j < 8; ++j) {                                       \
            float a = b1f[j];                                               \
            _Pragma("unroll")                                               \
            for (int i = 0; i < 8; ++i) a = dot2(hh[i], w1h[j][i], a);      \
            h1[j] = fmaxf(a, 0.0f);                                         \
        }                                                                   \
        half2v h1h[4];                                                      \
        _Pragma("unroll")                                                   \
        for (int i = 0; i < 4; ++i) h1h[i] = pk(h1[2*i], h1[2*i+1]);        \
        float a = b2f;                                                      \
        _Pragma("unroll")                                                   \
        for (int i = 0; i < 4; ++i) a = dot2(h1h[i], w2h[i], a);            \
        maxv = fmaxf(maxv, a);                                              \
    }

#pragma unroll
    for (int d = 0; d < DCH; d += 2) {
        STEP(bufA, d)
        STEP(bufB, d + 1)
    }
#undef STEP

    // Cross-wave max over the NW d-chunks.
    __shared__ float red[NW][64];
    red[wv][lane] = maxv;
    __syncthreads();
    if (threadIdx.x < 64) {
        float m = red[0][lane];
#pragma unroll
        for (int i = 1; i < NW; ++i) m = fmaxf(m, red[i][lane]);
        // sigmoid is monotone: max_d sigmoid(z) == sigmoid(max_d z)
        out[p] = 1.0f / (1.0f + __expf(-m));
    }
}

extern "C" void kernel_launch(void* const* d_in, const int* in_sizes, int n_in,
                              void* d_out, int out_size, void* d_ws, size_t ws_size,
                              hipStream_t stream) {
    const float* x1 = (const float*)d_in[0];
    fold_kernel<<<1, 64, 0, stream>>>(
        (const float*)d_in[1], (const float*)d_in[2], (const float*)d_in[3],
        (const float*)d_in[4], (const float*)d_in[5],
        (const float*)d_in[6], (const float*)d_in[7], (const float*)d_in[8],
        (const float*)d_in[9], (const float*)d_in[10],
        (const float*)d_in[11], (const float*)d_in[12]);
    mlp_kernel<<<NPIX / 64, NW * 64, 0, stream>>>(x1, (float*)d_out);
}

// Round 5
// 47.297 us; speedup vs baseline: 1.6068x; 1.2433x over previous
//
#include <hip/hip_runtime.h>

// Geometry (from reference): B=4, C=8, D=48, H=128, W=160
#define HW    20480      // H*W
#define DHW   983040     // D*H*W (channel stride)
#define CDHW  7864320    // C*D*H*W (batch stride)
#define DD    48
#define NPIX  81920      // B*H*W
#define NW    4          // waves per block = d-chunks
#define DCH   12         // d-slices per chunk
#define GROUPS 640       // NPIX / 128 (128 px per group, 2 per lane)

typedef _Float16 half2v  __attribute__((ext_vector_type(2)));
typedef float    float2v __attribute__((ext_vector_type(2)));

// Folded weights (BN absorbed), f16 pairs stored as uint bit patterns.
__device__ unsigned g_w0u[64];   // [o][i] : o<16, i<4  (pairs of input ch)
__device__ float    g_b0[16];
__device__ unsigned g_w1u[64];   // [j][i] : j<8,  i<8
__device__ float    g_b1[8];
__device__ unsigned g_w2u[4];
__device__ float    g_bias2;

static __device__ __forceinline__ float dot2(half2v a, half2v b, float c) {
#if __has_builtin(__builtin_amdgcn_fdot2)
    return __builtin_amdgcn_fdot2(a, b, c, false);
#else
    return fmaf((float)a.x, (float)b.x, fmaf((float)a.y, (float)b.y, c));
#endif
}

static __device__ __forceinline__ half2v pk(float a, float b) {
#if __has_builtin(__builtin_amdgcn_cvt_pkrtz)
    return __builtin_bit_cast(half2v, __builtin_amdgcn_cvt_pkrtz(a, b));
#else
    half2v h; h.x = (_Float16)a; h.y = (_Float16)b; return h;
#endif
}

static __device__ __forceinline__ unsigned pku(float a, float b) {
    return __builtin_bit_cast(unsigned, pk(a, b));
}

__global__ void fold_kernel(const float* __restrict__ w0, const float* __restrict__ g0,
                            const float* __restrict__ b0, const float* __restrict__ m0,
                            const float* __restrict__ v0,
                            const float* __restrict__ w1, const float* __restrict__ g1,
                            const float* __restrict__ b1, const float* __restrict__ m1,
                            const float* __restrict__ v1,
                            const float* __restrict__ w2, const float* __restrict__ bias2)
{
    int t = threadIdx.x;
    if (t < 16) {
        float sc = g0[t] * rsqrtf(v0[t] + 1e-5f);
        for (int i = 0; i < 4; ++i)
            g_w0u[t * 4 + i] = pku(w0[t * 8 + 2 * i] * sc, w0[t * 8 + 2 * i + 1] * sc);
        g_b0[t] = b0[t] - m0[t] * sc;
    } else if (t < 24) {
        int j = t - 16;
        float sc = g1[j] * rsqrtf(v1[j] + 1e-5f);
        for (int i = 0; i < 8; ++i)
            g_w1u[j * 8 + i] = pku(w1[j * 16 + 2 * i] * sc, w1[j * 16 + 2 * i + 1] * sc);
        g_b1[j] = b1[j] - m1[j] * sc;
    } else if (t == 24) {
        for (int i = 0; i < 4; ++i)
            g_w2u[i] = pku(w2[2 * i], w2[2 * i + 1]);
        g_bias2 = bias2[0];
    }
}

// One pixel's MLP: xh = 4 packed f16 channel-pairs. Returns logit.
static __device__ __forceinline__ float mlp_px(const half2v xh[4],
                                               const unsigned* w0s, const unsigned* b0s,
                                               const unsigned* w1v, const float* b1v,
                                               const unsigned* w2v, float b2v)
{
    float h0[16];
#pragma unroll
    for (int o = 0; o < 16; ++o) {
        float a = __uint_as_float(b0s[o]);
#pragma unroll
        for (int i = 0; i < 4; ++i)
            a = dot2(xh[i], __builtin_bit_cast(half2v, w0s[o * 4 + i]), a);
        h0[o] = fmaxf(a, 0.0f);
    }
    half2v hh[8];
#pragma unroll
    for (int i = 0; i < 8; ++i) hh[i] = pk(h0[2 * i], h0[2 * i + 1]);
    float h1[8];
#pragma unroll
    for (int j = 0; j < 8; ++j) {
        float a = b1v[j];
#pragma unroll
        for (int i = 0; i < 8; ++i)
            a = dot2(hh[i], __builtin_bit_cast(half2v, w1v[j * 8 + i]), a);
        h1[j] = fmaxf(a, 0.0f);
    }
    half2v hq[4];
#pragma unroll
    for (int i = 0; i < 4; ++i) hq[i] = pk(h1[2 * i], h1[2 * i + 1]);
    float a = b2v;
#pragma unroll
    for (int i = 0; i < 4; ++i)
        a = dot2(hq[i], __builtin_bit_cast(half2v, w2v[i]), a);
    return a;
}

__global__ __launch_bounds__(NW * 64, 1)
void mlp_kernel(const float* __restrict__ x, float* __restrict__ out)
{
    const int lane = threadIdx.x & 63;
    const int wv   = threadIdx.x >> 6;           // d-chunk id
    const int g    = blockIdx.x;                 // pixel group (128 px)
    const int b    = g / 160;                    // 160 groups per batch
    const int s0   = (g - b * 160) * 128 + lane * 2;
    const float* xp = x + (size_t)b * CDHW + s0 + (size_t)(wv * DCH) * HW;

    // ---- Layer-0 weights + biases -> SGPRs (wave-uniform; dot2 reads scalar src). ----
    unsigned w0s[64]; unsigned b0s[16];
#pragma unroll
    for (int k = 0; k < 64; ++k) {
        w0s[k] = __builtin_amdgcn_readfirstlane(g_w0u[k]);
        asm("" : "+s"(w0s[k]));
    }
#pragma unroll
    for (int k = 0; k < 16; ++k) {
        b0s[k] = __builtin_amdgcn_readfirstlane(__float_as_uint(g_b0[k]));
        asm("" : "+s"(b0s[k]));
    }
    // ---- Layer-1/2 weights -> VGPRs (fits comfortably now). ----
    unsigned w1v[64]; float b1v[8]; unsigned w2v[4]; float b2v;
#pragma unroll
    for (int k = 0; k < 64; ++k) { w1v[k] = g_w1u[k]; asm("" : "+v"(w1v[k])); }
#pragma unroll
    for (int k = 0; k < 8; ++k)  { b1v[k] = g_b1[k];  asm("" : "+v"(b1v[k])); }
#pragma unroll
    for (int k = 0; k < 4; ++k)  { w2v[k] = g_w2u[k]; asm("" : "+v"(w2v[k])); }
    b2v = g_bias2; asm("" : "+v"(b2v));

    float maxv0 = -1e30f, maxv1 = -1e30f;

    // Packed current slice: c0 = pixel 0 (lane*2), c1 = pixel 1 (lane*2+1).
    half2v c0[4], c1[4];
    {
        float2v ld[8];
#pragma unroll
        for (int c = 0; c < 8; ++c) ld[c] = *(const float2v*)(xp + (size_t)c * DHW);
#pragma unroll
        for (int i = 0; i < 4; ++i) {
            c0[i] = pk(ld[2 * i].x, ld[2 * i + 1].x);
            c1[i] = pk(ld[2 * i].y, ld[2 * i + 1].y);
        }
    }

#pragma unroll 2
    for (int d = 0; d < DCH; ++d) {
        float2v nx[8];
        if (d + 1 < DCH) {
            const float* xq = xp + (size_t)(d + 1) * HW;
#pragma unroll
            for (int c = 0; c < 8; ++c) nx[c] = *(const float2v*)(xq + (size_t)c * DHW);
        }

        maxv0 = fmaxf(maxv0, mlp_px(c0, w0s, b0s, w1v, b1v, w2v, b2v));
        maxv1 = fmaxf(maxv1, mlp_px(c1, w0s, b0s, w1v, b1v, w2v, b2v));

        if (d + 1 < DCH) {
#pragma unroll
            for (int i = 0; i < 4; ++i) {
                c0[i] = pk(nx[2 * i].x, nx[2 * i + 1].x);
                c1[i] = pk(nx[2 * i].y, nx[2 * i + 1].y);
            }
        }
    }

    // Cross-wave max over the NW d-chunks (2 px per lane).
    __shared__ float red[NW][128];
    red[wv][2 * lane]     = maxv0;
    red[wv][2 * lane + 1] = maxv1;
    __syncthreads();
    if (threadIdx.x < 128) {
        int t = threadIdx.x;
        float m = fmaxf(fmaxf(red[0][t], red[1][t]), fmaxf(red[2][t], red[3][t]));
        // sigmoid monotone: max_d sigmoid(z) == sigmoid(max_d z)
        out[(size_t)g * 128 + t] = 1.0f / (1.0f + __expf(-m));
    }
}

extern "C" void kernel_launch(void* const* d_in, const int* in_sizes, int n_in,
                              void* d_out, int out_size, void* d_ws, size_t ws_size,
                              hipStream_t stream) {
    const float* x1 = (const float*)d_in[0];
    fold_kernel<<<1, 64, 0, stream>>>(
        (const float*)d_in[1], (const float*)d_in[2], (const float*)d_in[3],
        (const float*)d_in[4], (const float*)d_in[5],
        (const float*)d_in[6], (const float*)d_in[7], (const float*)d_in[8],
        (const float*)d_in[9], (const float*)d_in[10],
        (const float*)d_in[11], (const float*)d_in[12]);
    mlp_kernel<<<GROUPS, NW * 64, 0, stream>>>(x1, (float*)d_out);
}